// Round 1
// baseline (340.518 us; speedup 1.0000x reference)
//
#include <hip/hip_runtime.h>
#include <hip/hip_bf16.h>

#define NB 2
#define NS 2048
#define NH 16
#define ND 128
#define HID2 2048
#define MROWS 4096   // NB*NS

typedef __bf16 bf16;
typedef bf16 bf16x8 __attribute__((ext_vector_type(8)));
typedef float f32x4 __attribute__((ext_vector_type(4)));
typedef unsigned int u32;

#define GLOBAL_AS __attribute__((address_space(1)))
#define LDS_AS __attribute__((address_space(3)))

__device__ __forceinline__ void async16(void* lds, const void* g) {
    __builtin_amdgcn_global_load_lds((const GLOBAL_AS u32*)g, (LDS_AS u32*)lds, 16, 0, 0);
}

// ---------------------------------------------------------------- converts
__global__ void cvt_f32_bf16(const float* __restrict__ src, bf16* __restrict__ dst, int n8) {
    int i = blockIdx.x * blockDim.x + threadIdx.x;
    if (i >= n8) return;
    const float4* s4 = (const float4*)src;
    float4 a = s4[2 * i], b = s4[2 * i + 1];
    bf16x8 o;
    o[0] = (bf16)a.x; o[1] = (bf16)a.y; o[2] = (bf16)a.z; o[3] = (bf16)a.w;
    o[4] = (bf16)b.x; o[5] = (bf16)b.y; o[6] = (bf16)b.z; o[7] = (bf16)b.w;
    ((bf16x8*)dst)[i] = o;
}

__global__ void qscale_kernel(const float* qr, const float* qi, const float* qm,
                              const float* kr, const float* ki, const float* km,
                              const float* vr, const float* vi, const float* vm,
                              float* out) {
    int i = blockIdx.x * blockDim.x + threadIdx.x;
    if (i >= HID2) return;
    out[i]            = sqrtf(qr[i] * qr[i] + qi[i] * qi[i]) * fabsf(qm[i]);
    out[HID2 + i]     = sqrtf(kr[i] * kr[i] + ki[i] * ki[i]) * fabsf(km[i]);
    out[2 * HID2 + i] = sqrtf(vr[i] * vr[i] + vi[i] * vi[i]) * fabsf(vm[i]);
}

// ---------------------------------------------------------------- GEMM core
// C = A @ Bt^T  (A [M,K] bf16 row-major, Bt [N,K] bf16 row-major)
// MODE 0: out bf16 = |acc + bias| * scale     (quantum epilogue)
// MODE 1: out f32  = acc + bias
template <int MODE>
__device__ __forceinline__ void gemm_core(const bf16* __restrict__ A, const bf16* __restrict__ Bt,
                                          const float* __restrict__ bias, const float* __restrict__ scale,
                                          void* __restrict__ Cout, int tm, int tn) {
    __shared__ bf16 At[128 * 64];
    __shared__ bf16 Bs[128 * 64];
    const int K = HID2;
    int tid = threadIdx.x;
    int wid = tid >> 6, lane = tid & 63;
    int wr = wid >> 1, wc = wid & 1;
    int l15 = lane & 15, l4 = lane >> 4;
    int rowA0 = tm * 128, rowB0 = tn * 128;

    const bf16* gA = A + (size_t)(rowA0 + wid * 8 + (lane >> 3)) * K + (lane & 7) * 8;
    const bf16* gB = Bt + (size_t)(rowB0 + wid * 8 + (lane >> 3)) * K + (lane & 7) * 8;
    char* lA = (char*)At + wid * 8 * 128;  // wave-uniform LDS chunk base (HW adds lane*16)
    char* lB = (char*)Bs + wid * 8 * 128;

    f32x4 acc[4][4] = {};

    for (int k0 = 0; k0 < K; k0 += 64) {
#pragma unroll
        for (int c = 0; c < 4; ++c) {
            async16(lA + c * 32 * 128, gA + (size_t)(c * 32) * K + k0);
            async16(lB + c * 32 * 128, gB + (size_t)(c * 32) * K + k0);
        }
        __syncthreads();
#pragma unroll
        for (int kk = 0; kk < 64; kk += 32) {
            bf16x8 af[4], bfr[4];
#pragma unroll
            for (int m = 0; m < 4; ++m)
                af[m] = *(const bf16x8*)(At + (wr * 64 + m * 16 + l15) * 64 + kk + l4 * 8);
#pragma unroll
            for (int n = 0; n < 4; ++n)
                bfr[n] = *(const bf16x8*)(Bs + (wc * 64 + n * 16 + l15) * 64 + kk + l4 * 8);
#pragma unroll
            for (int m = 0; m < 4; ++m)
#pragma unroll
                for (int n = 0; n < 4; ++n)
                    acc[m][n] = __builtin_amdgcn_mfma_f32_16x16x32_bf16(af[m], bfr[n], acc[m][n], 0, 0, 0);
        }
        __syncthreads();
    }

#pragma unroll
    for (int m = 0; m < 4; ++m) {
        int row = rowA0 + wr * 64 + m * 16 + l4 * 4;
#pragma unroll
        for (int n = 0; n < 4; ++n) {
            int col = rowB0 + wc * 64 + n * 16 + l15;
            float bv = bias[col];
            if (MODE == 0) {
                float sc = scale[col];
                bf16* Cp = (bf16*)Cout;
#pragma unroll
                for (int r = 0; r < 4; ++r)
                    Cp[(size_t)(row + r) * HID2 + col] = (bf16)(fabsf(acc[m][n][r] + bv) * sc);
            } else {
                float* Cp = (float*)Cout;
#pragma unroll
                for (int r = 0; r < 4; ++r)
                    Cp[(size_t)(row + r) * HID2 + col] = acc[m][n][r] + bv;
            }
        }
    }
}

__global__ __launch_bounds__(256, 2) void gemm_qkv_kernel(
    const bf16* __restrict__ X, const bf16* __restrict__ Wb,
    const float* __restrict__ bq, const float* __restrict__ bk, const float* __restrict__ bv,
    const float* __restrict__ scales, bf16* __restrict__ QKV) {
    int z = blockIdx.y;
    int tile = blockIdx.x;
    const bf16* W = Wb + (size_t)z * HID2 * HID2;
    const float* bias = (z == 0) ? bq : (z == 1) ? bk : bv;
    const float* scale = scales + z * HID2;
    bf16* out = QKV + (size_t)z * MROWS * HID2;
    gemm_core<0>(X, W, bias, scale, out, tile >> 4, tile & 15);
}

__global__ __launch_bounds__(256, 2) void gemm_out_kernel(
    const bf16* __restrict__ Ctx, const bf16* __restrict__ Wo,
    const float* __restrict__ bo, float* __restrict__ out) {
    int tile = blockIdx.x;
    gemm_core<1>(Ctx, Wo, bo, nullptr, out, tile >> 4, tile & 15);
}

// ---------------------------------------------------------------- V transpose
// Vb [B*S, HID] (per b,h block of cols) -> Vt [B][H][D][S]
__global__ void transpose_v(const bf16* __restrict__ Vb, bf16* __restrict__ Vt) {
    int bh = blockIdx.z;
    int b = bh >> 4, h = bh & 15;
    int s0 = blockIdx.x * 64, d0 = blockIdx.y * 64;
    int tid = threadIdx.x;
    __shared__ bf16 T[64][72];
    const bf16* src = Vb + ((size_t)b * NS + s0) * HID2 + h * ND + d0;
#pragma unroll
    for (int i = 0; i < 2; ++i) {
        int r = i * 32 + (tid >> 3);
        int c = (tid & 7) * 8;
        *(bf16x8*)(&T[r][c]) = *(const bf16x8*)(src + (size_t)r * HID2 + c);
    }
    __syncthreads();
    bf16* dst = Vt + ((size_t)(b * NH + h) * ND + d0) * NS + s0;
#pragma unroll
    for (int i = 0; i < 2; ++i) {
        int dr = i * 32 + (tid >> 3);
        int sc = (tid & 7) * 8;
        bf16x8 o;
#pragma unroll
        for (int j = 0; j < 8; ++j) o[j] = T[sc + j][dr];
        *(bf16x8*)(dst + (size_t)dr * NS + sc) = o;
    }
}

// ---------------------------------------------------------------- flash attention
// Per block: one (b,h), 128 q rows (4 waves x 32). K-tiles of 64 keys.
__global__ __launch_bounds__(256, 2) void flash_kernel(
    const bf16* __restrict__ Qb, const bf16* __restrict__ Kb, const bf16* __restrict__ Vt,
    const float* __restrict__ ent, const float* __restrict__ mask, bf16* __restrict__ Ctx) {
    int qt = blockIdx.x;   // 0..15
    int bh = blockIdx.y;   // 0..31
    int b = bh >> 4, h = bh & 15;
    int tid = threadIdx.x, wid = tid >> 6, lane = tid & 63;
    int l15 = lane & 15, l4 = lane >> 4;

    __shared__ bf16 Ks[64 * 136];   // [key][d] pad 8 -> 272B stride (16B aligned)
    __shared__ bf16 Vs[128 * 72];   // [d][key] pad 8 -> 144B stride
    __shared__ bf16 Ps[4][32 * 72]; // per-wave P [q][key] pad 8

    const bf16* Qp = Qb + ((size_t)b * NS + qt * 128) * HID2 + h * ND;
    const bf16* Kp = Kb + (size_t)b * NS * HID2 + h * ND;
    const bf16* Vp = Vt + (size_t)(b * NH + h) * ND * NS;
    const float* maskp = mask + (size_t)b * NS;

    // Q fragments held in registers for the whole kernel
    bf16x8 qf[2][4];
#pragma unroll
    for (int m = 0; m < 2; ++m)
#pragma unroll
        for (int kk = 0; kk < 4; ++kk)
            qf[m][kk] = *(const bf16x8*)(Qp + (size_t)(wid * 32 + m * 16 + l15) * HID2 + kk * 32 + l4 * 8);

    float bias_l = ent[h * NH + l15];  // bias[h, t] = ent[h][t%16], t%16 == lane&15
    const float RSQD = 0.08838834764831845f;  // 1/sqrt(128)

    float mrun[2][4], lrun[2][4];
#pragma unroll
    for (int m = 0; m < 2; ++m)
#pragma unroll
        for (int r = 0; r < 4; ++r) { mrun[m][r] = -INFINITY; lrun[m][r] = 0.f; }
    f32x4 oacc[2][8] = {};

    for (int kt = 0; kt < NS / 64; ++kt) {
        // stage K tile [64][128] and Vt tile [128][64]
#pragma unroll
        for (int i = 0; i < 4; ++i) {
            int r = i * 16 + (tid >> 4);
            int c = (tid & 15) * 8;
            *(bf16x8*)(&Ks[r * 136 + c]) = *(const bf16x8*)(Kp + (size_t)(kt * 64 + r) * HID2 + c);
            int d = i * 32 + (tid >> 3);
            int ck = (tid & 7) * 8;
            *(bf16x8*)(&Vs[d * 72 + ck]) = *(const bf16x8*)(Vp + (size_t)d * NS + kt * 64 + ck);
        }
        __syncthreads();

        // S = Q K^T  (per wave: 32 q x 64 keys)
        f32x4 s[2][4] = {};
#pragma unroll
        for (int kk = 0; kk < 4; ++kk) {
            bf16x8 kf[4];
#pragma unroll
            for (int n = 0; n < 4; ++n)
                kf[n] = *(const bf16x8*)(&Ks[(n * 16 + l15) * 136 + kk * 32 + l4 * 8]);
#pragma unroll
            for (int m = 0; m < 2; ++m)
#pragma unroll
                for (int n = 0; n < 4; ++n)
                    s[m][n] = __builtin_amdgcn_mfma_f32_16x16x32_bf16(qf[m][kk], kf[n], s[m][n], 0, 0, 0);
        }

        float mk[4];
#pragma unroll
        for (int n = 0; n < 4; ++n) mk[n] = maskp[kt * 64 + n * 16 + l15];

        // online softmax per q-row (row spread over the 16 lanes l15)
#pragma unroll
        for (int m = 0; m < 2; ++m) {
#pragma unroll
            for (int r = 0; r < 4; ++r) {
                float sv[4];
#pragma unroll
                for (int n = 0; n < 4; ++n) sv[n] = s[m][n][r] * RSQD + bias_l + mk[n];
                float tmax = fmaxf(fmaxf(sv[0], sv[1]), fmaxf(sv[2], sv[3]));
#pragma unroll
                for (int dd = 1; dd < 16; dd <<= 1) tmax = fmaxf(tmax, __shfl_xor(tmax, dd));
                float mnew = fmaxf(mrun[m][r], tmax);
                float corr = __expf(mrun[m][r] - mnew);
                mrun[m][r] = mnew;
                float p[4], ps = 0.f;
#pragma unroll
                for (int n = 0; n < 4; ++n) { p[n] = __expf(sv[n] - mnew); ps += p[n]; }
#pragma unroll
                for (int dd = 1; dd < 16; dd <<= 1) ps += __shfl_xor(ps, dd);
                lrun[m][r] = lrun[m][r] * corr + ps;
#pragma unroll
                for (int n = 0; n < 8; ++n) oacc[m][n][r] *= corr;
                int qrow = m * 16 + l4 * 4 + r;
#pragma unroll
                for (int n = 0; n < 4; ++n)
                    Ps[wid][qrow * 72 + n * 16 + l15] = (bf16)p[n];
            }
        }

        // ctx += P V   (A = P [32x64] from LDS, B = V via Vs[d][key])
#pragma unroll
        for (int kk = 0; kk < 2; ++kk) {
            bf16x8 pa[2], vb[8];
#pragma unroll
            for (int m = 0; m < 2; ++m)
                pa[m] = *(const bf16x8*)(&Ps[wid][(m * 16 + l15) * 72 + kk * 32 + l4 * 8]);
#pragma unroll
            for (int n = 0; n < 8; ++n)
                vb[n] = *(const bf16x8*)(&Vs[(n * 16 + l15) * 72 + kk * 32 + l4 * 8]);
#pragma unroll
            for (int m = 0; m < 2; ++m)
#pragma unroll
                for (int n = 0; n < 8; ++n)
                    oacc[m][n] = __builtin_amdgcn_mfma_f32_16x16x32_bf16(pa[m], vb[n], oacc[m][n], 0, 0, 0);
        }
        __syncthreads();
    }

    // epilogue: ctx / l, store bf16
#pragma unroll
    for (int m = 0; m < 2; ++m)
#pragma unroll
        for (int r = 0; r < 4; ++r) {
            float inv = 1.0f / lrun[m][r];
            int row = qt * 128 + wid * 32 + m * 16 + l4 * 4 + r;
            bf16* Cp = Ctx + ((size_t)b * NS + row) * HID2 + h * ND;
#pragma unroll
            for (int n = 0; n < 8; ++n)
                Cp[n * 16 + l15] = (bf16)(oacc[m][n][r] * inv);
        }
}

// ---------------------------------------------------------------- launch
extern "C" void kernel_launch(void* const* d_in, const int* in_sizes, int n_in,
                              void* d_out, int out_size, void* d_ws, size_t ws_size,
                              hipStream_t stream) {
    const float* hidden = (const float*)d_in[0];
    const float* mask   = (const float*)d_in[1];
    const float* q_real = (const float*)d_in[2];
    const float* q_imag = (const float*)d_in[3];
    const float* q_mag  = (const float*)d_in[5];
    const float* k_real = (const float*)d_in[6];
    const float* k_imag = (const float*)d_in[7];
    const float* k_mag  = (const float*)d_in[9];
    const float* v_real = (const float*)d_in[10];
    const float* v_imag = (const float*)d_in[11];
    const float* v_mag  = (const float*)d_in[13];
    const float* Wq = (const float*)d_in[14];
    const float* bq = (const float*)d_in[15];
    const float* Wk = (const float*)d_in[16];
    const float* bk = (const float*)d_in[17];
    const float* Wv = (const float*)d_in[18];
    const float* bv = (const float*)d_in[19];
    const float* Wo = (const float*)d_in[20];
    const float* bo = (const float*)d_in[21];
    const float* ent = (const float*)d_in[22];

    char* ws = (char*)d_ws;
    bf16* Xb    = (bf16*)(ws);
    bf16* Wb    = (bf16*)(ws + 16777216);        // Wq,Wk,Wv bf16 stacked
    bf16* Wob   = (bf16*)(ws + 41943040);
    bf16* QKV   = (bf16*)(ws + 50331648);        // Q,K,V bf16 stacked
    bf16* Vt    = (bf16*)(ws + 100663296);
    bf16* Ctx   = (bf16*)(ws + 117440512);
    float* scales = (float*)(ws + 134217728);

    const int W8 = HID2 * HID2 / 8;

    cvt_f32_bf16<<<4096, 256, 0, stream>>>(hidden, Xb, MROWS * HID2 / 8);
    cvt_f32_bf16<<<2048, 256, 0, stream>>>(Wq, Wb, W8);
    cvt_f32_bf16<<<2048, 256, 0, stream>>>(Wk, Wb + (size_t)HID2 * HID2, W8);
    cvt_f32_bf16<<<2048, 256, 0, stream>>>(Wv, Wb + (size_t)2 * HID2 * HID2, W8);
    cvt_f32_bf16<<<2048, 256, 0, stream>>>(Wo, Wob, W8);
    qscale_kernel<<<8, 256, 0, stream>>>(q_real, q_imag, q_mag, k_real, k_imag, k_mag,
                                         v_real, v_imag, v_mag, scales);
    gemm_qkv_kernel<<<dim3(512, 3), 256, 0, stream>>>(Xb, Wb, bq, bk, bv, scales, QKV);
    const bf16* Vb = QKV + (size_t)2 * MROWS * HID2;
    transpose_v<<<dim3(32, 2, 32), 256, 0, stream>>>(Vb, Vt);
    flash_kernel<<<dim3(16, 32), 256, 0, stream>>>(QKV, QKV + (size_t)MROWS * HID2, Vt, ent, mask, Ctx);
    gemm_out_kernel<<<512, 256, 0, stream>>>(Ctx, Wob, bo, (float*)d_out);
}

// Round 3
// 299.267 us; speedup vs baseline: 1.1378x; 1.1378x over previous
//
#include <hip/hip_runtime.h>
#include <hip/hip_bf16.h>

#define NB 2
#define NS 2048
#define NH 16
#define ND 128
#define HID2 2048
#define MROWS 4096   // NB*NS

typedef __bf16 bf16;
typedef bf16 bf16x8 __attribute__((ext_vector_type(8)));
typedef bf16 bf16x4 __attribute__((ext_vector_type(4)));
typedef float f32x4 __attribute__((ext_vector_type(4)));
typedef unsigned int u32;

#define GLOBAL_AS __attribute__((address_space(1)))
#define LDS_AS __attribute__((address_space(3)))

__device__ __forceinline__ void async16(void* lds, const void* g) {
    __builtin_amdgcn_global_load_lds((const GLOBAL_AS u32*)g, (LDS_AS u32*)lds, 16, 0, 0);
}

// ---------------------------------------------------------------- converts
__global__ void cvt_f32_bf16(const float* __restrict__ src, bf16* __restrict__ dst, int n8) {
    int i = blockIdx.x * blockDim.x + threadIdx.x;
    if (i >= n8) return;
    const float4* s4 = (const float4*)src;
    float4 a = s4[2 * i], b = s4[2 * i + 1];
    bf16x8 o;
    o[0] = (bf16)a.x; o[1] = (bf16)a.y; o[2] = (bf16)a.z; o[3] = (bf16)a.w;
    o[4] = (bf16)b.x; o[5] = (bf16)b.y; o[6] = (bf16)b.z; o[7] = (bf16)b.w;
    ((bf16x8*)dst)[i] = o;
}

__global__ void qscale_kernel(const float* qr, const float* qi, const float* qm,
                              const float* kr, const float* ki, const float* km,
                              const float* vr, const float* vi, const float* vm,
                              float* out) {
    int i = blockIdx.x * blockDim.x + threadIdx.x;
    if (i >= HID2) return;
    out[i]            = sqrtf(qr[i] * qr[i] + qi[i] * qi[i]) * fabsf(qm[i]);
    out[HID2 + i]     = sqrtf(kr[i] * kr[i] + ki[i] * ki[i]) * fabsf(km[i]);
    out[2 * HID2 + i] = sqrtf(vr[i] * vr[i] + vi[i] * vi[i]) * fabsf(vm[i]);
}

// ---------------------------------------------------------------- GEMM core
template <int MODE>
__device__ __forceinline__ void gemm_core(const bf16* __restrict__ A, const bf16* __restrict__ Bt,
                                          const float* __restrict__ bias, const float* __restrict__ scale,
                                          void* __restrict__ Cout, int tm, int tn) {
    __shared__ bf16 At[128 * 64];
    __shared__ bf16 Bs[128 * 64];
    const int K = HID2;
    int tid = threadIdx.x;
    int wid = tid >> 6, lane = tid & 63;
    int wr = wid >> 1, wc = wid & 1;
    int l15 = lane & 15, l4 = lane >> 4;
    int rowA0 = tm * 128, rowB0 = tn * 128;

    const bf16* gA = A + (size_t)(rowA0 + wid * 8 + (lane >> 3)) * K + (lane & 7) * 8;
    const bf16* gB = Bt + (size_t)(rowB0 + wid * 8 + (lane >> 3)) * K + (lane & 7) * 8;
    char* lA = (char*)At + wid * 8 * 128;
    char* lB = (char*)Bs + wid * 8 * 128;

    f32x4 acc[4][4] = {};

    for (int k0 = 0; k0 < K; k0 += 64) {
#pragma unroll
        for (int c = 0; c < 4; ++c) {
            async16(lA + c * 32 * 128, gA + (size_t)(c * 32) * K + k0);
            async16(lB + c * 32 * 128, gB + (size_t)(c * 32) * K + k0);
        }
        __syncthreads();
#pragma unroll
        for (int kk = 0; kk < 64; kk += 32) {
            bf16x8 af[4], bfr[4];
#pragma unroll
            for (int m = 0; m < 4; ++m)
                af[m] = *(const bf16x8*)(At + (wr * 64 + m * 16 + l15) * 64 + kk + l4 * 8);
#pragma unroll
            for (int n = 0; n < 4; ++n)
                bfr[n] = *(const bf16x8*)(Bs + (wc * 64 + n * 16 + l15) * 64 + kk + l4 * 8);
#pragma unroll
            for (int m = 0; m < 4; ++m)
#pragma unroll
                for (int n = 0; n < 4; ++n)
                    acc[m][n] = __builtin_amdgcn_mfma_f32_16x16x32_bf16(af[m], bfr[n], acc[m][n], 0, 0, 0);
        }
        __syncthreads();
    }

#pragma unroll
    for (int m = 0; m < 4; ++m) {
        int row = rowA0 + wr * 64 + m * 16 + l4 * 4;
#pragma unroll
        for (int n = 0; n < 4; ++n) {
            int col = rowB0 + wc * 64 + n * 16 + l15;
            float bv = bias[col];
            if (MODE == 0) {
                float sc = scale[col];
                bf16* Cp = (bf16*)Cout;
#pragma unroll
                for (int r = 0; r < 4; ++r)
                    Cp[(size_t)(row + r) * HID2 + col] = (bf16)(fabsf(acc[m][n][r] + bv) * sc);
            } else {
                float* Cp = (float*)Cout;
#pragma unroll
                for (int r = 0; r < 4; ++r)
                    Cp[(size_t)(row + r) * HID2 + col] = acc[m][n][r] + bv;
            }
        }
    }
}

__global__ __launch_bounds__(256, 2) void gemm_qkv_kernel(
    const bf16* __restrict__ X, const bf16* __restrict__ Wb,
    const float* __restrict__ bq, const float* __restrict__ bk, const float* __restrict__ bv,
    const float* __restrict__ scales, bf16* __restrict__ QKV) {
    int z = blockIdx.y;
    int tile = blockIdx.x;
    const bf16* W = Wb + (size_t)z * HID2 * HID2;
    const float* bias = (z == 0) ? bq : (z == 1) ? bk : bv;
    const float* scale = scales + z * HID2;
    bf16* out = QKV + (size_t)z * MROWS * HID2;
    gemm_core<0>(X, W, bias, scale, out, tile >> 4, tile & 15);
}

__global__ __launch_bounds__(256, 2) void gemm_out_kernel(
    const bf16* __restrict__ Ctx, const bf16* __restrict__ Wo,
    const float* __restrict__ bo, float* __restrict__ out) {
    int tile = blockIdx.x;
    gemm_core<1>(Ctx, Wo, bo, nullptr, out, tile >> 4, tile & 15);
}

// ---------------------------------------------------------------- V transpose
__global__ void transpose_v(const bf16* __restrict__ Vb, bf16* __restrict__ Vt) {
    int bh = blockIdx.z;
    int b = bh >> 4, h = bh & 15;
    int s0 = blockIdx.x * 64, d0 = blockIdx.y * 64;
    int tid = threadIdx.x;
    __shared__ bf16 T[64][72];
    const bf16* src = Vb + ((size_t)b * NS + s0) * HID2 + h * ND + d0;
#pragma unroll
    for (int i = 0; i < 2; ++i) {
        int r = i * 32 + (tid >> 3);
        int c = (tid & 7) * 8;
        *(bf16x8*)(&T[r][c]) = *(const bf16x8*)(src + (size_t)r * HID2 + c);
    }
    __syncthreads();
    bf16* dst = Vt + ((size_t)(b * NH + h) * ND + d0) * NS + s0;
#pragma unroll
    for (int i = 0; i < 2; ++i) {
        int dr = i * 32 + (tid >> 3);
        int sc = (tid & 7) * 8;
        bf16x8 o;
#pragma unroll
        for (int j = 0; j < 8; ++j) o[j] = T[sc + j][dr];
        *(bf16x8*)(dst + (size_t)dr * NS + sc) = o;
    }
}

// ---------------------------------------------------------------- flash attention (v2)
// Swapped QK^T: S'[key][q] = mfma(A=K, B=Q). Softmax reduction over keys is
// in-reg fmax/add + 2 shfl_xor (lane bits 4,5). Defer-max skips rescale.
__device__ __forceinline__ void stage_load(const bf16* __restrict__ Kp, const bf16* __restrict__ Vp,
                                           int kt, int tid, bf16x8 kreg[4], bf16x8 vreg[4]) {
#pragma unroll
    for (int i = 0; i < 4; ++i) {
        kreg[i] = *(const bf16x8*)(Kp + (size_t)(kt * 64 + i * 16 + (tid >> 4)) * HID2 + (tid & 15) * 8);
        vreg[i] = *(const bf16x8*)(Vp + (size_t)(i * 32 + (tid >> 3)) * NS + kt * 64 + (tid & 7) * 8);
    }
}

__global__ __launch_bounds__(256, 2) void flash_kernel(
    const bf16* __restrict__ Qb, const bf16* __restrict__ Kb, const bf16* __restrict__ Vt,
    const float* __restrict__ ent, const float* __restrict__ mask, bf16* __restrict__ Ctx) {
    int qt = blockIdx.x;   // 0..15
    int bh = blockIdx.y;   // 0..31
    int b = bh >> 4, h = bh & 15;
    int tid = threadIdx.x, wid = tid >> 6, lane = tid & 63;
    int l15 = lane & 15, l4 = lane >> 4;

    __shared__ bf16 Ks[64 * 136];   // [key][d]  pad -> 272B row stride
    __shared__ bf16 Vs[128 * 72];   // [d][key]  pad -> 144B row stride
    __shared__ bf16 Ps[4][32 * 72]; // per-wave P [q][key]

    const bf16* Qp = Qb + ((size_t)b * NS + qt * 128) * HID2 + h * ND;
    const bf16* Kp = Kb + (size_t)b * NS * HID2 + h * ND;
    const bf16* Vp = Vt + (size_t)(b * NH + h) * ND * NS;
    const float* maskp = mask + (size_t)b * NS;

    // Q fragments (used as MFMA B-operand: lane l15 = q-col, elems = d)
    bf16x8 qf[2][4];
#pragma unroll
    for (int m = 0; m < 2; ++m)
#pragma unroll
        for (int kk = 0; kk < 4; ++kk)
            qf[m][kk] = *(const bf16x8*)(Qp + (size_t)(wid * 32 + m * 16 + l15) * HID2 + kk * 32 + l4 * 8);

    // bias for key t: ent[h][t%16]; in swapped layout key%16 = l4*4 + r
    float eb[4];
#pragma unroll
    for (int r = 0; r < 4; ++r) eb[r] = ent[h * NH + l4 * 4 + r];
    const float RSQD = 0.08838834764831845f;  // 1/sqrt(128)

    float mrun[2], lrun[2];  // per q = m*16 + l15, replicated over l4 groups
    mrun[0] = mrun[1] = -INFINITY;
    lrun[0] = lrun[1] = 0.f;
    f32x4 oacc[2][8] = {};

    bf16x8 kreg[4], vreg[4];
    stage_load(Kp, Vp, 0, tid, kreg, vreg);
#pragma unroll
    for (int i = 0; i < 4; ++i) {
        *(bf16x8*)(&Ks[(i * 16 + (tid >> 4)) * 136 + (tid & 15) * 8]) = kreg[i];
        *(bf16x8*)(&Vs[(i * 32 + (tid >> 3)) * 72 + (tid & 7) * 8]) = vreg[i];
    }

    for (int kt = 0; kt < NS / 64; ++kt) {
        __syncthreads();   // staged tile visible
        if (kt + 1 < NS / 64) stage_load(Kp, Vp, kt + 1, tid, kreg, vreg);  // prefetch to regs

        // S' = K Q^T  (rows = keys, cols = q)
        f32x4 s[2][4] = {};
#pragma unroll
        for (int kk = 0; kk < 4; ++kk) {
            bf16x8 kf[4];
#pragma unroll
            for (int n = 0; n < 4; ++n)
                kf[n] = *(const bf16x8*)(&Ks[(n * 16 + l15) * 136 + kk * 32 + l4 * 8]);
#pragma unroll
            for (int m = 0; m < 2; ++m)
#pragma unroll
                for (int n = 0; n < 4; ++n)
                    s[m][n] = __builtin_amdgcn_mfma_f32_16x16x32_bf16(kf[n], qf[m][kk], s[m][n], 0, 0, 0);
        }

        float4 mk[4];
#pragma unroll
        for (int n = 0; n < 4; ++n)
            mk[n] = *(const float4*)(maskp + kt * 64 + n * 16 + l4 * 4);

#pragma unroll
        for (int mq = 0; mq < 2; ++mq) {
            float sv[4][4];
#pragma unroll
            for (int n = 0; n < 4; ++n) {
                sv[n][0] = s[mq][n][0] * RSQD + eb[0] + mk[n].x;
                sv[n][1] = s[mq][n][1] * RSQD + eb[1] + mk[n].y;
                sv[n][2] = s[mq][n][2] * RSQD + eb[2] + mk[n].z;
                sv[n][3] = s[mq][n][3] * RSQD + eb[3] + mk[n].w;
            }
            float tmax = sv[0][0];
#pragma unroll
            for (int n = 0; n < 4; ++n)
#pragma unroll
                for (int r = 0; r < 4; ++r) tmax = fmaxf(tmax, sv[n][r]);
            tmax = fmaxf(tmax, __shfl_xor(tmax, 16));
            tmax = fmaxf(tmax, __shfl_xor(tmax, 32));

            if (__any(tmax > mrun[mq] + 8.0f)) {   // defer-max: rare after tile 0
                float mnew = fmaxf(mrun[mq], tmax);
                float corr = __expf(mrun[mq] - mnew);
                mrun[mq] = mnew;
                lrun[mq] *= corr;
#pragma unroll
                for (int r = 0; r < 4; ++r) {
                    float cr = __shfl(corr, l4 * 4 + r);  // corr lives at lane l15==row
#pragma unroll
                    for (int n = 0; n < 8; ++n) oacc[mq][n][r] *= cr;
                }
            }

            float psum = 0.f;
#pragma unroll
            for (int n = 0; n < 4; ++n) {
                bf16x4 pv;
#pragma unroll
                for (int r = 0; r < 4; ++r) {
                    float p = __expf(sv[n][r] - mrun[mq]);
                    psum += p;
                    pv[r] = (bf16)p;
                }
                // P[q = mq*16+l15][key = n*16 + l4*4 .. +3]  (b64 store)
                *(bf16x4*)(&Ps[wid][(mq * 16 + l15) * 72 + n * 16 + l4 * 4]) = pv;
            }
            psum += __shfl_xor(psum, 16);
            psum += __shfl_xor(psum, 32);
            lrun[mq] += psum;
        }

        // ctx += P V
#pragma unroll
        for (int kk = 0; kk < 2; ++kk) {
            bf16x8 pa[2], vb[8];
#pragma unroll
            for (int m = 0; m < 2; ++m)
                pa[m] = *(const bf16x8*)(&Ps[wid][(m * 16 + l15) * 72 + kk * 32 + l4 * 8]);
#pragma unroll
            for (int n = 0; n < 8; ++n)
                vb[n] = *(const bf16x8*)(&Vs[(n * 16 + l15) * 72 + kk * 32 + l4 * 8]);
#pragma unroll
            for (int m = 0; m < 2; ++m)
#pragma unroll
                for (int n = 0; n < 8; ++n)
                    oacc[m][n] = __builtin_amdgcn_mfma_f32_16x16x32_bf16(pa[m], vb[n], oacc[m][n], 0, 0, 0);
        }
        __syncthreads();   // all waves done reading Ks/Vs
        if (kt + 1 < NS / 64) {
#pragma unroll
            for (int i = 0; i < 4; ++i) {
                *(bf16x8*)(&Ks[(i * 16 + (tid >> 4)) * 136 + (tid & 15) * 8]) = kreg[i];
                *(bf16x8*)(&Vs[(i * 32 + (tid >> 3)) * 72 + (tid & 7) * 8]) = vreg[i];
            }
        }
    }

    // epilogue: ctx / l  (1/l lives at lane l15==q; broadcast to row-domain)
#pragma unroll
    for (int m = 0; m < 2; ++m) {
        float inv = 1.0f / lrun[m];
        float invr[4];
#pragma unroll
        for (int r = 0; r < 4; ++r) invr[r] = __shfl(inv, l4 * 4 + r);
#pragma unroll
        for (int r = 0; r < 4; ++r) {
            int row = qt * 128 + wid * 32 + m * 16 + l4 * 4 + r;
            bf16* Cp = Ctx + ((size_t)b * NS + row) * HID2 + h * ND;
#pragma unroll
            for (int n = 0; n < 8; ++n)
                Cp[n * 16 + l15] = (bf16)(oacc[m][n][r] * invr[r]);
        }
    }
}

// ---------------------------------------------------------------- launch
extern "C" void kernel_launch(void* const* d_in, const int* in_sizes, int n_in,
                              void* d_out, int out_size, void* d_ws, size_t ws_size,
                              hipStream_t stream) {
    const float* hidden = (const float*)d_in[0];
    const float* mask   = (const float*)d_in[1];
    const float* q_real = (const float*)d_in[2];
    const float* q_imag = (const float*)d_in[3];
    const float* q_mag  = (const float*)d_in[5];
    const float* k_real = (const float*)d_in[6];
    const float* k_imag = (const float*)d_in[7];
    const float* k_mag  = (const float*)d_in[9];
    const float* v_real = (const float*)d_in[10];
    const float* v_imag = (const float*)d_in[11];
    const float* v_mag  = (const float*)d_in[13];
    const float* Wq = (const float*)d_in[14];
    const float* bq = (const float*)d_in[15];
    const float* Wk = (const float*)d_in[16];
    const float* bk = (const float*)d_in[17];
    const float* Wv = (const float*)d_in[18];
    const float* bv = (const float*)d_in[19];
    const float* Wo = (const float*)d_in[20];
    const float* bo = (const float*)d_in[21];
    const float* ent = (const float*)d_in[22];

    char* ws = (char*)d_ws;
    bf16* Xb    = (bf16*)(ws);
    bf16* Wb    = (bf16*)(ws + 16777216);
    bf16* Wob   = (bf16*)(ws + 41943040);
    bf16* QKV   = (bf16*)(ws + 50331648);
    bf16* Vt    = (bf16*)(ws + 100663296);
    bf16* Ctx   = (bf16*)(ws + 117440512);
    float* scales = (float*)(ws + 134217728);

    const int W8 = HID2 * HID2 / 8;

    cvt_f32_bf16<<<4096, 256, 0, stream>>>(hidden, Xb, MROWS * HID2 / 8);
    cvt_f32_bf16<<<2048, 256, 0, stream>>>(Wq, Wb, W8);
    cvt_f32_bf16<<<2048, 256, 0, stream>>>(Wk, Wb + (size_t)HID2 * HID2, W8);
    cvt_f32_bf16<<<2048, 256, 0, stream>>>(Wv, Wb + (size_t)2 * HID2 * HID2, W8);
    cvt_f32_bf16<<<2048, 256, 0, stream>>>(Wo, Wob, W8);
    qscale_kernel<<<8, 256, 0, stream>>>(q_real, q_imag, q_mag, k_real, k_imag, k_mag,
                                         v_real, v_imag, v_mag, scales);
    gemm_qkv_kernel<<<dim3(512, 3), 256, 0, stream>>>(Xb, Wb, bq, bk, bv, scales, QKV);
    const bf16* Vb = QKV + (size_t)2 * MROWS * HID2;
    transpose_v<<<dim3(32, 2, 32), 256, 0, stream>>>(Vb, Vt);
    flash_kernel<<<dim3(16, 32), 256, 0, stream>>>(QKV, QKV + (size_t)MROWS * HID2, Vt, ent, mask, Ctx);
    gemm_out_kernel<<<512, 256, 0, stream>>>(Ctx, Wob, bo, (float*)d_out);
}